// Round 4
// baseline (3499.410 us; speedup 1.0000x reference)
//
#include <hip/hip_runtime.h>
#include <math.h>

#define LATENT 256
#define HIDDEN 512
#define MAXN   64
#define BATCH  128
#define NPAIR  2016   // 64*63/2
#define G3     1536   // 3*HIDDEN

// ---------------------------------------------------------------------------
// pre_kernel: blocks 0..191  -> ZC projections (+ adj diagonal zero in 0..31)
//             blocks 192..447 -> WAB precompute (folded adj_W1 @ node_W)
// ---------------------------------------------------------------------------
__global__ __launch_bounds__(256) void pre_kernel(
    const float* __restrict__ z, const float* __restrict__ pe,
    const float* __restrict__ emb, const float* __restrict__ W_pre,
    const float* __restrict__ b_pre, float* __restrict__ ZC,
    float* __restrict__ adj,
    const float* __restrict__ adj_W1, const float* __restrict__ node_W,
    float* __restrict__ WAB)
{
  __shared__ float s1[256];
  __shared__ float s2[256];
  int blk = blockIdx.x;
  int o = threadIdx.x;      // 0..255
  if (blk < 192) {
    int row = blk;
    if (row < 32) {
      int x = row * 256 + o;            // 0..8191
      int b = x >> 6, d = x & 63;
      adj[(size_t)b * 4096 + d * 65] = 0.f;
    }
    const float* wr = W_pre + (size_t)o * 512;
    if (row < 128) {
      s1[o] = z[row * 256 + o];
      __syncthreads();
      float acc = 0.f;
      #pragma unroll 8
      for (int k = 0; k < 256; k += 4) {
        float4 w4 = *(const float4*)(wr + k);
        float4 x4 = *(const float4*)(&s1[k]);
        acc += x4.x * w4.x; acc += x4.y * w4.y; acc += x4.z * w4.z; acc += x4.w * w4.w;
      }
      ZC[row * 256 + o] = acc;
    } else {
      int m = row - 128;
      s1[o] = pe[m * 256 + o];
      s2[o] = emb[m * 256 + o];
      __syncthreads();
      float acc = b_pre[o];
      #pragma unroll 8
      for (int k = 0; k < 256; k += 4) {
        float4 w4 = *(const float4*)(wr + k);
        float4 x4 = *(const float4*)(&s1[k]);
        acc += x4.x * w4.x; acc += x4.y * w4.y; acc += x4.z * w4.z; acc += x4.w * w4.w;
      }
      #pragma unroll 8
      for (int k = 0; k < 256; k += 4) {
        float4 w4 = *(const float4*)(wr + 256 + k);
        float4 x4 = *(const float4*)(&s2[k]);
        acc += x4.x * w4.x; acc += x4.y * w4.y; acc += x4.z * w4.z; acc += x4.w * w4.w;
      }
      ZC[row * 256 + o] = acc;
    }
  } else {
    // WAB: idx in [0,256): kb = idx&1, o-group = (idx>>1)&63, sel = idx>>7
    int idx = blk - 192;
    int k = (idx & 1) * 256 + o;            // 0..511
    int o0 = ((idx >> 1) & 63) * 8;
    int sel = idx >> 7;
    const float* a1 = adj_W1 + (sel ? 512 : 0);
    float acc[8] = {0.f, 0.f, 0.f, 0.f, 0.f, 0.f, 0.f, 0.f};
    for (int j = 0; j < 512; j++) {
      float w = node_W[(size_t)j * 512 + k];
      #pragma unroll
      for (int oo = 0; oo < 8; oo++)
        acc[oo] += a1[(size_t)(o0 + oo) * 1024 + j] * w;
    }
    #pragma unroll
    for (int oo = 0; oo < 8; oo++)
      WAB[(size_t)(sel * 512 + o0 + oo) * 512 + k] = acc[oo];
  }
}

// ---------------------------------------------------------------------------
// Generic f32 GEMM: C[M,N] = A[M,K] @ W[N,K]^T (+bias), optional per-row mask
// ---------------------------------------------------------------------------
template<bool MASK>
__global__ __launch_bounds__(256) void gemm_kernel(
    const float* __restrict__ A, int lda,
    const float* __restrict__ W, int ldw,
    const float* __restrict__ bias,
    float* __restrict__ C, int ldc,
    int M, int N, int K,
    const int* __restrict__ n_nodes)
{
  __shared__ float As[16][136];
  __shared__ float Ws[16][136];
  const int tid = threadIdx.x;
  const int tx = tid & 15, ty = tid >> 4;
  const int row0 = blockIdx.y * 128, col0 = blockIdx.x * 128;

  float acc[8][8];
  #pragma unroll
  for (int i = 0; i < 8; i++)
    #pragma unroll
    for (int j = 0; j < 8; j++) acc[i][j] = 0.f;

  for (int k0 = 0; k0 < K; k0 += 16) {
    #pragma unroll
    for (int s = 0; s < 2; s++) {
      int q = tid + 256 * s;
      int r = q >> 2;
      int c4 = (q & 3) << 2;
      int gm = row0 + r;
      float4 v = make_float4(0.f, 0.f, 0.f, 0.f);
      if (gm < M) {
        v = *(const float4*)(A + (size_t)gm * lda + k0 + c4);
        if (MASK) {
          int bb = gm >> 6, tt = gm & 63;
          if (tt >= n_nodes[bb]) v = make_float4(0.f, 0.f, 0.f, 0.f);
        }
      }
      As[c4 + 0][r] = v.x; As[c4 + 1][r] = v.y; As[c4 + 2][r] = v.z; As[c4 + 3][r] = v.w;
      int gn = col0 + r;
      float4 w = *(const float4*)(W + (size_t)gn * ldw + k0 + c4);
      Ws[c4 + 0][r] = w.x; Ws[c4 + 1][r] = w.y; Ws[c4 + 2][r] = w.z; Ws[c4 + 3][r] = w.w;
    }
    __syncthreads();
    #pragma unroll
    for (int kk = 0; kk < 16; kk++) {
      float4 a0 = *(const float4*)&As[kk][ty * 8];
      float4 a1 = *(const float4*)&As[kk][ty * 8 + 4];
      float4 b0 = *(const float4*)&Ws[kk][tx * 8];
      float4 b1 = *(const float4*)&Ws[kk][tx * 8 + 4];
      float av[8] = {a0.x, a0.y, a0.z, a0.w, a1.x, a1.y, a1.z, a1.w};
      float bv[8] = {b0.x, b0.y, b0.z, b0.w, b1.x, b1.y, b1.z, b1.w};
      #pragma unroll
      for (int i = 0; i < 8; i++)
        #pragma unroll
        for (int j = 0; j < 8; j++)
          acc[i][j] += av[i] * bv[j];
    }
    __syncthreads();
  }

  float bb[8];
  #pragma unroll
  for (int j = 0; j < 8; j++) bb[j] = bias ? bias[col0 + tx * 8 + j] : 0.f;
  #pragma unroll
  for (int i = 0; i < 8; i++) {
    int gm = row0 + ty * 8 + i;
    if (gm < M) {
      float* out = C + (size_t)gm * ldc + col0 + tx * 8;
      float4 o0 = make_float4(acc[i][0] + bb[0], acc[i][1] + bb[1], acc[i][2] + bb[2], acc[i][3] + bb[3]);
      float4 o1 = make_float4(acc[i][4] + bb[4], acc[i][5] + bb[5], acc[i][6] + bb[6], acc[i][7] + bb[7]);
      *(float4*)out = o0;
      *(float4*)(out + 4) = o1;
    }
  }
}

// ---------------------------------------------------------------------------
// 3-plane pipelined GRU step. Launch s (s = 0..65):
//   plane 0 (L0):  t = s    : h1[t] = GRUcell(gh = h1[t-1]@Whh0^T, gi = ZCW)
//   plane 1 (GI):  t = s-1  : GI[t] = h1[t]@Wih1^T + bih1       (next launch)
//   plane 2 (L1):  t = s-2  : h2[t] = GRUcell(gh = h2[t-1]@Whh1^T, gi = GI[t])
// Block: 512 thr = 8 o x (64 grp x 2 b) -> covers ALL 128 b x 8 o x 3 gates.
// Grid (64, 3) = 192 blocks, 1 block/CU (80 KB LDS), 2 waves/SIMD.
// Per kk-step/wave: 5 broadcast ds_read_b128 vs 24 FMA -> VALU-bound.
// ---------------------------------------------------------------------------
__global__ __launch_bounds__(512) void gru_pipe2_kernel(
    const float* __restrict__ Whh0, const float* __restrict__ bhh0,
    float* __restrict__ H1,
    const float* __restrict__ ZCW, const float* __restrict__ bih0,
    const int* __restrict__ n_nodes,
    const float* __restrict__ Wih1, const float* __restrict__ bih1,
    const float* __restrict__ Whh1, const float* __restrict__ bhh1,
    float* __restrict__ H2, float* __restrict__ GI, int s)
{
  __shared__ float w_s[24][132];    // 3 gates x 8 o rows, one 128-K chunk
  __shared__ float h_s[128][132];   // all 128 b rows, one 128-K chunk
  const int tid = threadIdx.x;
  const int ol = tid & 7;           // 0..7
  const int blg = tid >> 3;         // 0..63 (x2 b)
  const int o0 = blockIdx.x * 8;
  const int o = o0 + ol;
  const int plane = blockIdx.y;

  const float* W; const float* Hsrc; int t, tt;
  if (plane == 0)      { t = s;     if (t > 63) return; W = Whh0; Hsrc = H1; tt = t - 1; }
  else if (plane == 1) { t = s - 1; if (t < 0 || t > 63) return; W = Wih1; Hsrc = H1; tt = t; }
  else                 { t = s - 2; if (t < 0) return; W = Whh1; Hsrc = H2; tt = t - 1; }

  float accr[2] = {0.f, 0.f}, accz[2] = {0.f, 0.f}, accn[2] = {0.f, 0.f};

  const bool do_dot = (plane == 1) || (t > 0);
  if (do_dot) {
    float4 wreg0, wreg1, hreg[8];
    auto load_chunk = [&](int k0) {
      {
        int q = tid;                 // 0..511 of 768 w-float4s
        int r = q >> 5, c4 = (q & 31) << 2;
        int g = r >> 3;
        wreg0 = *(const float4*)(W + (size_t)((g << 9) + o0 + (r & 7)) * 512 + k0 + c4);
      }
      if (tid < 256) {
        int q = 512 + tid;
        int r = q >> 5, c4 = (q & 31) << 2;
        int g = r >> 3;
        wreg1 = *(const float4*)(W + (size_t)((g << 9) + o0 + (r & 7)) * 512 + k0 + c4);
      }
      #pragma unroll
      for (int u = 0; u < 8; u++) {
        int q = tid + (u << 9);      // 0..4095 h-float4s
        int r = q >> 5, c4 = (q & 31) << 2;
        hreg[u] = *(const float4*)(Hsrc + ((size_t)(r * 64 + tt)) * 512 + k0 + c4);
      }
    };
    auto commit = [&]() {
      {
        int q = tid; int r = q >> 5, c4 = (q & 31) << 2;
        *(float4*)&w_s[r][c4] = wreg0;
      }
      if (tid < 256) {
        int q = 512 + tid; int r = q >> 5, c4 = (q & 31) << 2;
        *(float4*)&w_s[r][c4] = wreg1;
      }
      #pragma unroll
      for (int u = 0; u < 8; u++) {
        int q = tid + (u << 9); int r = q >> 5, c4 = (q & 31) << 2;
        *(float4*)&h_s[r][c4] = hreg[u];
      }
    };
    load_chunk(0);
    const int r0 = blg * 2, r1 = r0 + 1;
    for (int c = 0; c < 4; c++) {
      __syncthreads();
      commit();
      __syncthreads();
      if (c < 3) load_chunk((c + 1) * 128);
      #pragma unroll 8
      for (int kk = 0; kk < 128; kk += 4) {
        float4 wr = *(const float4*)&w_s[ol][kk];
        float4 wz = *(const float4*)&w_s[8 + ol][kk];
        float4 wn = *(const float4*)&w_s[16 + ol][kk];
        float4 h0 = *(const float4*)&h_s[r0][kk];
        float4 h1v = *(const float4*)&h_s[r1][kk];
        accr[0] += h0.x*wr.x + h0.y*wr.y + h0.z*wr.z + h0.w*wr.w;
        accz[0] += h0.x*wz.x + h0.y*wz.y + h0.z*wz.z + h0.w*wz.w;
        accn[0] += h0.x*wn.x + h0.y*wn.y + h0.z*wn.z + h0.w*wn.w;
        accr[1] += h1v.x*wr.x + h1v.y*wr.y + h1v.z*wr.z + h1v.w*wr.w;
        accz[1] += h1v.x*wz.x + h1v.y*wz.y + h1v.z*wz.z + h1v.w*wz.w;
        accn[1] += h1v.x*wn.x + h1v.y*wn.y + h1v.z*wn.z + h1v.w*wn.w;
      }
    }
  }

  if (plane == 0) {
    float zt_r = ZCW[(size_t)(128 + t) * G3 + o];
    float zt_z = ZCW[(size_t)(128 + t) * G3 + 512 + o];
    float zt_n = ZCW[(size_t)(128 + t) * G3 + 1024 + o];
    float b_r = bih0[o], b_z = bih0[512 + o], b_n = bih0[1024 + o];
    float c_r = bhh0[o], c_z = bhh0[512 + o], c_n = bhh0[1024 + o];
    #pragma unroll
    for (int i = 0; i < 2; i++) {
      int b = blg * 2 + i;
      bool mk = t < n_nodes[b];
      float ir  = (mk ? ZCW[(size_t)b * G3 + o] + zt_r : 0.f) + b_r;
      float iz  = (mk ? ZCW[(size_t)b * G3 + 512 + o] + zt_z : 0.f) + b_z;
      float inn = (mk ? ZCW[(size_t)b * G3 + 1024 + o] + zt_n : 0.f) + b_n;
      float rg = 1.f / (1.f + expf(-(ir + accr[i] + c_r)));
      float zg = 1.f / (1.f + expf(-(iz + accz[i] + c_z)));
      float ng = tanhf(inn + rg * (accn[i] + c_n));
      float hp = (t > 0) ? H1[((size_t)(b * 64 + t - 1)) * 512 + o] : 0.f;
      H1[((size_t)(b * 64 + t)) * 512 + o] = (1.f - zg) * ng + zg * hp;
    }
  } else if (plane == 1) {
    float b_r = bih1[o], b_z = bih1[512 + o], b_n = bih1[1024 + o];
    #pragma unroll
    for (int i = 0; i < 2; i++) {
      int b = blg * 2 + i;
      size_t base = ((size_t)(b * 64 + t)) * G3;
      GI[base + o]        = accr[i] + b_r;
      GI[base + 512 + o]  = accz[i] + b_z;
      GI[base + 1024 + o] = accn[i] + b_n;
    }
  } else {
    float c_r = bhh1[o], c_z = bhh1[512 + o], c_n = bhh1[1024 + o];
    #pragma unroll
    for (int i = 0; i < 2; i++) {
      int b = blg * 2 + i;
      size_t base = ((size_t)(b * 64 + t)) * G3;
      float ir  = GI[base + o];
      float iz  = GI[base + 512 + o];
      float inn = GI[base + 1024 + o];
      float rg = 1.f / (1.f + expf(-(ir + accr[i] + c_r)));
      float zg = 1.f / (1.f + expf(-(iz + accz[i] + c_z)));
      float ng = tanhf(inn + rg * (accn[i] + c_n));
      float hp = (t > 0) ? H2[((size_t)(b * 64 + t - 1)) * 512 + o] : 0.f;
      H2[((size_t)(b * 64 + t)) * 512 + o] = (1.f - zg) * ng + zg * hp;
    }
  }
}

// ---------------------------------------------------------------------------
// Pair kernel: one wave per (b, pair). hmid = relu(A_i + B_j + b1),
// logits = hmid @ W2^T + b2, gumbel hard argmax, symmetric scatter.
// ---------------------------------------------------------------------------
__global__ __launch_bounds__(256) void pair_kernel(
    const float* __restrict__ AB, const float* __restrict__ b1,
    const float* __restrict__ W2, const float* __restrict__ b2,
    const float* __restrict__ gu, const int* __restrict__ n_nodes,
    float* __restrict__ adj)
{
  int wid = blockIdx.x * 4 + (threadIdx.x >> 6);
  int lane = threadIdx.x & 63;
  int b = wid / NPAIR;
  int p = wid - b * NPAIR;

  float fp = (float)p;
  int i = (int)((127.0f - sqrtf(16129.0f - 8.0f * fp)) * 0.5f);
  if (i < 0) i = 0;
  if (i > 62) i = 62;
  while (i < 62 && (i + 1) * (126 - i) / 2 <= p) i++;
  while (i > 0 && i * (127 - i) / 2 > p) i--;
  int j = p - i * (127 - i) / 2 + i + 1;

  const float* arow = AB + ((size_t)(b * 64 + i)) * 1024;
  const float* brow = AB + ((size_t)(b * 64 + j)) * 1024 + 512;
  int k0 = lane * 8;

  float4 a0 = *(const float4*)(arow + k0);
  float4 a1 = *(const float4*)(arow + k0 + 4);
  float4 q0 = *(const float4*)(brow + k0);
  float4 q1 = *(const float4*)(brow + k0 + 4);
  float4 c0 = *(const float4*)(b1 + k0);
  float4 c1 = *(const float4*)(b1 + k0 + 4);

  float h0 = fmaxf(a0.x + q0.x + c0.x, 0.f);
  float h1 = fmaxf(a0.y + q0.y + c0.y, 0.f);
  float h2 = fmaxf(a0.z + q0.z + c0.z, 0.f);
  float h3 = fmaxf(a0.w + q0.w + c0.w, 0.f);
  float h4 = fmaxf(a1.x + q1.x + c1.x, 0.f);
  float h5 = fmaxf(a1.y + q1.y + c1.y, 0.f);
  float h6 = fmaxf(a1.z + q1.z + c1.z, 0.f);
  float h7 = fmaxf(a1.w + q1.w + c1.w, 0.f);

  float4 w00 = *(const float4*)(W2 + k0);
  float4 w01 = *(const float4*)(W2 + k0 + 4);
  float4 w10 = *(const float4*)(W2 + 512 + k0);
  float4 w11 = *(const float4*)(W2 + 512 + k0 + 4);

  float acc0 = h0 * w00.x + h1 * w00.y + h2 * w00.z + h3 * w00.w
             + h4 * w01.x + h5 * w01.y + h6 * w01.z + h7 * w01.w;
  float acc1 = h0 * w10.x + h1 * w10.y + h2 * w10.z + h3 * w10.w
             + h4 * w11.x + h5 * w11.y + h6 * w11.z + h7 * w11.w;

  #pragma unroll
  for (int off = 32; off > 0; off >>= 1) {
    acc0 += __shfl_xor(acc0, off, 64);
    acc1 += __shfl_xor(acc1, off, 64);
  }

  if (lane == 0) {
    float s0 = acc0 + b2[0];
    float s1 = acc1 + b2[1];
    const float* u = gu + ((size_t)(b * NPAIR + p)) * 2;
    float g0 = -logf(-logf(u[0] + 1e-10f) + 1e-10f);
    float g1 = -logf(-logf(u[1] + 1e-10f) + 1e-10f);
    int n = n_nodes[b];
    float val = 0.f;
    if (i < n && j < n) val = ((s0 + g0) >= (s1 + g1)) ? 1.f : 0.f;
    adj[(size_t)b * 4096 + i * 64 + j] = val;
    adj[(size_t)b * 4096 + j * 64 + i] = val;
  }
}

// ---------------------------------------------------------------------------
extern "C" void kernel_launch(void* const* d_in, const int* in_sizes, int n_in,
                              void* d_out, int out_size, void* d_ws, size_t ws_size,
                              hipStream_t stream)
{
  (void)in_sizes; (void)n_in; (void)out_size; (void)ws_size;

  const float* z       = (const float*)d_in[0];
  const int*   n_nodes = (const int*)d_in[1];
  // d_in[2] = n_edges (unused by reference)
  const float* gu      = (const float*)d_in[3];
  const float* emb     = (const float*)d_in[4];
  const float* pe      = (const float*)d_in[5];
  const float* W_pre   = (const float*)d_in[6];
  const float* b_pre   = (const float*)d_in[7];
  const float* Wih0    = (const float*)d_in[8];
  const float* Whh0    = (const float*)d_in[9];
  const float* bih0    = (const float*)d_in[10];
  const float* bhh0    = (const float*)d_in[11];
  const float* Wih1    = (const float*)d_in[12];
  const float* Whh1    = (const float*)d_in[13];
  const float* bih1    = (const float*)d_in[14];
  const float* bhh1    = (const float*)d_in[15];
  const float* node_W  = (const float*)d_in[16];
  const float* adj_W1  = (const float*)d_in[17];
  const float* adj_b1  = (const float*)d_in[18];
  const float* adj_W2  = (const float*)d_in[19];
  const float* adj_b2  = (const float*)d_in[20];
  float* adj = (float*)d_out;

  // workspace layout (bytes)
  char* ws = (char*)d_ws;
  float* ZC  = (float*)(ws + 0);         // 192 x 256
  float* ZCW = (float*)(ws + 196608);    // 192 x 1536
  float* WAB = (float*)(ws + 1376256);   // 1024 x 512
  float* H1  = (float*)(ws + 3473408);   // 8192 x 512
  float* H2  = (float*)(ws + 20250624);  // 8192 x 512
  float* GI  = (float*)(ws + 37027840);  // 8192 x 1536
  float* AB  = GI;                       // aliases GI (dead by then)

  // 1) ZC projections + diag zero + WAB precompute (one launch)
  pre_kernel<<<448, 256, 0, stream>>>(z, pe, emb, W_pre, b_pre, ZC, adj,
                                      adj_W1, node_W, WAB);

  // 2) ZCW = ZC @ Wih0^T   (192 x 1536, K=256)
  gemm_kernel<false><<<dim3(12, 2), 256, 0, stream>>>(
      ZC, 256, Wih0, 256, nullptr, ZCW, 1536, 192, 1536, 256, nullptr);

  // 3) depth-3 pipelined GRU scan: 66 launches cover L0, GI-projection, L1
  for (int s = 0; s <= 65; s++)
    gru_pipe2_kernel<<<dim3(64, 3), 512, 0, stream>>>(
        Whh0, bhh0, H1, ZCW, bih0, n_nodes,
        Wih1, bih1, Whh1, bhh1, H2, GI, s);

  // 4) AB = (mask * H2) @ WAB^T   (8192 x 1024, K=512)
  gemm_kernel<true><<<dim3(8, 64), 256, 0, stream>>>(
      H2, 512, WAB, 512, nullptr, AB, 1024, 8192, 1024, 512, n_nodes);

  // 5) output pairs (diagonal already zeroed in step 1)
  pair_kernel<<<64512, 256, 0, stream>>>(AB, adj_b1, adj_W2, adj_b2, gu, n_nodes, adj);
}

// Round 5
// 2028.290 us; speedup vs baseline: 1.7253x; 1.7253x over previous
//
#include <hip/hip_runtime.h>
#include <math.h>

#define LATENT 256
#define HIDDEN 512
#define MAXN   64
#define BATCH  128
#define NPAIR  2016   // 64*63/2
#define G3     1536   // 3*HIDDEN

// Ht / H2t ring slot stride (floats): [512 o][128 b]
#define HT_S   65536
// GIt ring slot stride (floats): [1536 r][128 b]
#define GIT_S  196608
// one transposed weight matrix WT[k][o][4] (floats)
#define WT_S   1048576

// ---------------------------------------------------------------------------
// pre_kernel:
//   blocks   0..191 -> ZC projections (+ adj diagonal zero in blocks 0..31)
//   blocks 192..447 -> WAB precompute (folded adj_W1 @ node_W)
//   blocks 448..735 -> weight transposes: WT[mat][k][o][g] = W[g*512+o][k]
//                      mat 0=Whh0, 1=Wih1, 2=Whh1  (pad g=3 unwritten/unused)
// ---------------------------------------------------------------------------
__global__ __launch_bounds__(256) void pre_kernel(
    const float* __restrict__ z, const float* __restrict__ pe,
    const float* __restrict__ emb, const float* __restrict__ W_pre,
    const float* __restrict__ b_pre, float* __restrict__ ZC,
    float* __restrict__ adj,
    const float* __restrict__ adj_W1, const float* __restrict__ node_W,
    float* __restrict__ WAB,
    const float* __restrict__ Whh0, const float* __restrict__ Wih1,
    const float* __restrict__ Whh1, float* __restrict__ WT)
{
  __shared__ float s1[256];
  __shared__ float s2[256];
  int blk = blockIdx.x;
  int o = threadIdx.x;      // 0..255
  if (blk < 192) {
    int row = blk;
    if (row < 32) {
      int x = row * 256 + o;            // 0..8191
      int b = x >> 6, d = x & 63;
      adj[(size_t)b * 4096 + d * 65] = 0.f;
    }
    const float* wr = W_pre + (size_t)o * 512;
    if (row < 128) {
      s1[o] = z[row * 256 + o];
      __syncthreads();
      float acc = 0.f;
      #pragma unroll 8
      for (int k = 0; k < 256; k += 4) {
        float4 w4 = *(const float4*)(wr + k);
        float4 x4 = *(const float4*)(&s1[k]);
        acc += x4.x * w4.x; acc += x4.y * w4.y; acc += x4.z * w4.z; acc += x4.w * w4.w;
      }
      ZC[row * 256 + o] = acc;
    } else {
      int m = row - 128;
      s1[o] = pe[m * 256 + o];
      s2[o] = emb[m * 256 + o];
      __syncthreads();
      float acc = b_pre[o];
      #pragma unroll 8
      for (int k = 0; k < 256; k += 4) {
        float4 w4 = *(const float4*)(wr + k);
        float4 x4 = *(const float4*)(&s1[k]);
        acc += x4.x * w4.x; acc += x4.y * w4.y; acc += x4.z * w4.z; acc += x4.w * w4.w;
      }
      #pragma unroll 8
      for (int k = 0; k < 256; k += 4) {
        float4 w4 = *(const float4*)(wr + 256 + k);
        float4 x4 = *(const float4*)(&s2[k]);
        acc += x4.x * w4.x; acc += x4.y * w4.y; acc += x4.z * w4.z; acc += x4.w * w4.w;
      }
      ZC[row * 256 + o] = acc;
    }
  } else if (blk < 448) {
    // WAB: idx in [0,256): kb = idx&1, o-group = (idx>>1)&63, sel = idx>>7
    int idx = blk - 192;
    int k = (idx & 1) * 256 + o;            // 0..511
    int o0 = ((idx >> 1) & 63) * 8;
    int sel = idx >> 7;
    const float* a1 = adj_W1 + (sel ? 512 : 0);
    float acc[8] = {0.f, 0.f, 0.f, 0.f, 0.f, 0.f, 0.f, 0.f};
    for (int j = 0; j < 512; j++) {
      float w = node_W[(size_t)j * 512 + k];
      #pragma unroll
      for (int oo = 0; oo < 8; oo++)
        acc[oo] += a1[(size_t)(o0 + oo) * 1024 + j] * w;
    }
    #pragma unroll
    for (int oo = 0; oo < 8; oo++)
      WAB[(size_t)(sel * 512 + o0 + oo) * 512 + k] = acc[oo];
  } else {
    // weight transpose: 288 blocks, each 16 rows of one 1536x512 matrix
    int idx2 = blk - 448;             // 0..287
    int mat = idx2 / 96;              // 0..2
    int r0 = (idx2 % 96) * 16;
    const float* Wsrc = (mat == 0) ? Whh0 : (mat == 1) ? Wih1 : Whh1;
    float* Wd = WT + (size_t)mat * WT_S;
    int r = r0 + (o >> 4);            // 16 rows, 16 threads per row
    int oo = r & 511, g = r >> 9;
    int k0 = (o & 15) * 32;
    const float* src = Wsrc + (size_t)r * 512 + k0;
    for (int k = 0; k < 32; k++)
      Wd[((size_t)(k0 + k) * 512 + oo) * 4 + g] = src[k];
  }
}

// ---------------------------------------------------------------------------
// Generic f32 GEMM: C[M,N] = A[M,K] @ W[N,K]^T (+bias), optional per-row mask
// ---------------------------------------------------------------------------
template<bool MASK>
__global__ __launch_bounds__(256) void gemm_kernel(
    const float* __restrict__ A, int lda,
    const float* __restrict__ W, int ldw,
    const float* __restrict__ bias,
    float* __restrict__ C, int ldc,
    int M, int N, int K,
    const int* __restrict__ n_nodes)
{
  __shared__ float As[16][136];
  __shared__ float Ws[16][136];
  const int tid = threadIdx.x;
  const int tx = tid & 15, ty = tid >> 4;
  const int row0 = blockIdx.y * 128, col0 = blockIdx.x * 128;

  float acc[8][8];
  #pragma unroll
  for (int i = 0; i < 8; i++)
    #pragma unroll
    for (int j = 0; j < 8; j++) acc[i][j] = 0.f;

  for (int k0 = 0; k0 < K; k0 += 16) {
    #pragma unroll
    for (int s = 0; s < 2; s++) {
      int q = tid + 256 * s;
      int r = q >> 2;
      int c4 = (q & 3) << 2;
      int gm = row0 + r;
      float4 v = make_float4(0.f, 0.f, 0.f, 0.f);
      if (gm < M) {
        v = *(const float4*)(A + (size_t)gm * lda + k0 + c4);
        if (MASK) {
          int bb = gm >> 6, tt = gm & 63;
          if (tt >= n_nodes[bb]) v = make_float4(0.f, 0.f, 0.f, 0.f);
        }
      }
      As[c4 + 0][r] = v.x; As[c4 + 1][r] = v.y; As[c4 + 2][r] = v.z; As[c4 + 3][r] = v.w;
      int gn = col0 + r;
      float4 w = *(const float4*)(W + (size_t)gn * ldw + k0 + c4);
      Ws[c4 + 0][r] = w.x; Ws[c4 + 1][r] = w.y; Ws[c4 + 2][r] = w.z; Ws[c4 + 3][r] = w.w;
    }
    __syncthreads();
    #pragma unroll
    for (int kk = 0; kk < 16; kk++) {
      float4 a0 = *(const float4*)&As[kk][ty * 8];
      float4 a1 = *(const float4*)&As[kk][ty * 8 + 4];
      float4 b0 = *(const float4*)&Ws[kk][tx * 8];
      float4 b1 = *(const float4*)&Ws[kk][tx * 8 + 4];
      float av[8] = {a0.x, a0.y, a0.z, a0.w, a1.x, a1.y, a1.z, a1.w};
      float bv[8] = {b0.x, b0.y, b0.z, b0.w, b1.x, b1.y, b1.z, b1.w};
      #pragma unroll
      for (int i = 0; i < 8; i++)
        #pragma unroll
        for (int j = 0; j < 8; j++)
          acc[i][j] += av[i] * bv[j];
    }
    __syncthreads();
  }

  float bb[8];
  #pragma unroll
  for (int j = 0; j < 8; j++) bb[j] = bias ? bias[col0 + tx * 8 + j] : 0.f;
  #pragma unroll
  for (int i = 0; i < 8; i++) {
    int gm = row0 + ty * 8 + i;
    if (gm < M) {
      float* out = C + (size_t)gm * ldc + col0 + tx * 8;
      float4 o0 = make_float4(acc[i][0] + bb[0], acc[i][1] + bb[1], acc[i][2] + bb[2], acc[i][3] + bb[3]);
      float4 o1 = make_float4(acc[i][4] + bb[4], acc[i][5] + bb[5], acc[i][6] + bb[6], acc[i][7] + bb[7]);
      *(float4*)out = o0;
      *(float4*)(out + 4) = o1;
    }
  }
}

// ---------------------------------------------------------------------------
// v5 GRU step: 3 planes per launch, all-global streaming dot (NO LDS in the
// main loop), split-K across 8 waves, LDS only for the 8-way partial reduce.
//   plane 0: t=s    h1[t] = cell(h1[t-1]@Whh0^T, ZCW)      -> Ht1 ring
//   plane 1: t=s-1  GIt[t] = h1[t]@Wih1^T + bih1            -> GIt ring
//   plane 2: t=s-2  h2[t] = cell(h2[t-1]@Whh1^T, GIt[t])   -> H2t ring + H2row
// Layouts: Ht/H2t/GIt are [ring2][row][128 b]; WT[k][o][4] packs 3 gates in a
// float4 (w4.x=r, w4.y=z, w4.z=n, w4.w=pad).
// Block: 512 thr = 8 waves; block tile = 32 b x (8 o x 3 gates); wave w owns
// k in [64w, 64w+64). Lane: bg=l&7 (4 b), rg=l>>3 (1 o); per k: 2 coalesced
// float4 global loads -> 12 FMA. Grid (256, 3) = 768 blocks = 3 blocks/CU.
// ---------------------------------------------------------------------------
__global__ __launch_bounds__(512) void gru_v5_kernel(
    const float* __restrict__ WT,
    const float* __restrict__ ZCW,
    const float* __restrict__ bih0, const float* __restrict__ bhh0,
    const float* __restrict__ bih1, const float* __restrict__ bhh1,
    const int* __restrict__ n_nodes,
    float* __restrict__ Ht1, float* __restrict__ GIt,
    float* __restrict__ H2t, float* __restrict__ H2row,
    int s)
{
  __shared__ float p_s[8][3][8][32];   // 24 KB partials
  const int tid = threadIdx.x;
  const int plane = blockIdx.y;
  const int o0 = (blockIdx.x >> 2) * 8;
  const int b0 = (blockIdx.x & 3) * 32;

  int t; const float* Wmat; const float* Hin; bool dd;
  if (plane == 0)      { t = s;     Wmat = WT;            Hin = Ht1 + ((t - 1) & 1) * HT_S; dd = (t > 0); }
  else if (plane == 1) { t = s - 1; Wmat = WT + WT_S;     Hin = Ht1 + (t & 1) * HT_S;       dd = true; }
  else                 { t = s - 2; Wmat = WT + 2 * WT_S; Hin = H2t + ((t - 1) & 1) * HT_S; dd = (t > 0); }
  if (t < 0 || t > 63) return;

  float acc[3][4] = {{0.f, 0.f, 0.f, 0.f}, {0.f, 0.f, 0.f, 0.f}, {0.f, 0.f, 0.f, 0.f}};
  const int w = tid >> 6, l = tid & 63;
  const int bg = l & 7, rg = l >> 3;

  if (dd) {
    const float* hp_ = Hin + b0 + bg * 4 + (size_t)(w << 6) * 128;
    const float* wp_ = Wmat + (size_t)(o0 + rg) * 4 + (size_t)(w << 6) * 2048;
    #pragma unroll 4
    for (int k = 0; k < 64; k++) {
      float4 h4 = *(const float4*)(hp_ + (size_t)k * 128);
      float4 w4 = *(const float4*)(wp_ + (size_t)k * 2048);
      acc[0][0] += h4.x * w4.x; acc[0][1] += h4.y * w4.x; acc[0][2] += h4.z * w4.x; acc[0][3] += h4.w * w4.x;
      acc[1][0] += h4.x * w4.y; acc[1][1] += h4.y * w4.y; acc[1][2] += h4.z * w4.y; acc[1][3] += h4.w * w4.y;
      acc[2][0] += h4.x * w4.z; acc[2][1] += h4.y * w4.z; acc[2][2] += h4.z * w4.z; acc[2][3] += h4.w * w4.z;
    }
  }

  *(float4*)&p_s[w][0][rg][bg * 4] = make_float4(acc[0][0], acc[0][1], acc[0][2], acc[0][3]);
  *(float4*)&p_s[w][1][rg][bg * 4] = make_float4(acc[1][0], acc[1][1], acc[1][2], acc[1][3]);
  *(float4*)&p_s[w][2][rg][bg * 4] = make_float4(acc[2][0], acc[2][1], acc[2][2], acc[2][3]);
  __syncthreads();

  if (tid < 256) {
    int b = tid & 31, oi = tid >> 5;
    float s0 = 0.f, s1 = 0.f, s2 = 0.f;
    #pragma unroll
    for (int ww = 0; ww < 8; ww++) {
      s0 += p_s[ww][0][oi][b];
      s1 += p_s[ww][1][oi][b];
      s2 += p_s[ww][2][oi][b];
    }
    const int B = b0 + b, O = o0 + oi;

    if (plane == 0) {
      bool mk = t < n_nodes[B];
      float zr = mk ? ZCW[(size_t)B * G3 + O]        + ZCW[(size_t)(128 + t) * G3 + O]        : 0.f;
      float zz = mk ? ZCW[(size_t)B * G3 + 512 + O]  + ZCW[(size_t)(128 + t) * G3 + 512 + O]  : 0.f;
      float zn = mk ? ZCW[(size_t)B * G3 + 1024 + O] + ZCW[(size_t)(128 + t) * G3 + 1024 + O] : 0.f;
      float ir = zr + bih0[O], iz = zz + bih0[512 + O], inn = zn + bih0[1024 + O];
      float hr = s0 + bhh0[O], hz = s1 + bhh0[512 + O], hn = s2 + bhh0[1024 + O];
      float rg_ = 1.f / (1.f + expf(-(ir + hr)));
      float zg  = 1.f / (1.f + expf(-(iz + hz)));
      float ng  = tanhf(inn + rg_ * hn);
      float hp = (t > 0) ? Ht1[((t - 1) & 1) * HT_S + O * 128 + B] : 0.f;
      Ht1[(t & 1) * HT_S + O * 128 + B] = (1.f - zg) * ng + zg * hp;
    } else if (plane == 1) {
      size_t gb = (size_t)(t & 1) * GIT_S;
      GIt[gb + (size_t)O * 128 + B]          = s0 + bih1[O];
      GIt[gb + (size_t)(512 + O) * 128 + B]  = s1 + bih1[512 + O];
      GIt[gb + (size_t)(1024 + O) * 128 + B] = s2 + bih1[1024 + O];
    } else {
      size_t gb = (size_t)(t & 1) * GIT_S;
      float ir  = GIt[gb + (size_t)O * 128 + B];
      float iz  = GIt[gb + (size_t)(512 + O) * 128 + B];
      float inn = GIt[gb + (size_t)(1024 + O) * 128 + B];
      float hr = s0 + bhh1[O], hz = s1 + bhh1[512 + O], hn = s2 + bhh1[1024 + O];
      float rg_ = 1.f / (1.f + expf(-(ir + hr)));
      float zg  = 1.f / (1.f + expf(-(iz + hz)));
      float ng  = tanhf(inn + rg_ * hn);
      float hp = (t > 0) ? H2t[((t - 1) & 1) * HT_S + O * 128 + B] : 0.f;
      float hnew = (1.f - zg) * ng + zg * hp;
      H2t[(t & 1) * HT_S + O * 128 + B] = hnew;
      H2row[((size_t)(B * 64 + t)) * 512 + O] = hnew;
    }
  }
}

// ---------------------------------------------------------------------------
// Pair kernel: one wave per (b, pair). hmid = relu(A_i + B_j + b1),
// logits = hmid @ W2^T + b2, gumbel hard argmax, symmetric scatter.
// ---------------------------------------------------------------------------
__global__ __launch_bounds__(256) void pair_kernel(
    const float* __restrict__ AB, const float* __restrict__ b1,
    const float* __restrict__ W2, const float* __restrict__ b2,
    const float* __restrict__ gu, const int* __restrict__ n_nodes,
    float* __restrict__ adj)
{
  int wid = blockIdx.x * 4 + (threadIdx.x >> 6);
  int lane = threadIdx.x & 63;
  int b = wid / NPAIR;
  int p = wid - b * NPAIR;

  float fp = (float)p;
  int i = (int)((127.0f - sqrtf(16129.0f - 8.0f * fp)) * 0.5f);
  if (i < 0) i = 0;
  if (i > 62) i = 62;
  while (i < 62 && (i + 1) * (126 - i) / 2 <= p) i++;
  while (i > 0 && i * (127 - i) / 2 > p) i--;
  int j = p - i * (127 - i) / 2 + i + 1;

  const float* arow = AB + ((size_t)(b * 64 + i)) * 1024;
  const float* brow = AB + ((size_t)(b * 64 + j)) * 1024 + 512;
  int k0 = lane * 8;

  float4 a0 = *(const float4*)(arow + k0);
  float4 a1 = *(const float4*)(arow + k0 + 4);
  float4 q0 = *(const float4*)(brow + k0);
  float4 q1 = *(const float4*)(brow + k0 + 4);
  float4 c0 = *(const float4*)(b1 + k0);
  float4 c1 = *(const float4*)(b1 + k0 + 4);

  float h0 = fmaxf(a0.x + q0.x + c0.x, 0.f);
  float h1 = fmaxf(a0.y + q0.y + c0.y, 0.f);
  float h2 = fmaxf(a0.z + q0.z + c0.z, 0.f);
  float h3 = fmaxf(a0.w + q0.w + c0.w, 0.f);
  float h4 = fmaxf(a1.x + q1.x + c1.x, 0.f);
  float h5 = fmaxf(a1.y + q1.y + c1.y, 0.f);
  float h6 = fmaxf(a1.z + q1.z + c1.z, 0.f);
  float h7 = fmaxf(a1.w + q1.w + c1.w, 0.f);

  float4 w00 = *(const float4*)(W2 + k0);
  float4 w01 = *(const float4*)(W2 + k0 + 4);
  float4 w10 = *(const float4*)(W2 + 512 + k0);
  float4 w11 = *(const float4*)(W2 + 512 + k0 + 4);

  float acc0 = h0 * w00.x + h1 * w00.y + h2 * w00.z + h3 * w00.w
             + h4 * w01.x + h5 * w01.y + h6 * w01.z + h7 * w01.w;
  float acc1 = h0 * w10.x + h1 * w10.y + h2 * w10.z + h3 * w10.w
             + h4 * w11.x + h5 * w11.y + h6 * w11.z + h7 * w11.w;

  #pragma unroll
  for (int off = 32; off > 0; off >>= 1) {
    acc0 += __shfl_xor(acc0, off, 64);
    acc1 += __shfl_xor(acc1, off, 64);
  }

  if (lane == 0) {
    float s0 = acc0 + b2[0];
    float s1 = acc1 + b2[1];
    const float* u = gu + ((size_t)(b * NPAIR + p)) * 2;
    float g0 = -logf(-logf(u[0] + 1e-10f) + 1e-10f);
    float g1 = -logf(-logf(u[1] + 1e-10f) + 1e-10f);
    int n = n_nodes[b];
    float val = 0.f;
    if (i < n && j < n) val = ((s0 + g0) >= (s1 + g1)) ? 1.f : 0.f;
    adj[(size_t)b * 4096 + i * 64 + j] = val;
    adj[(size_t)b * 4096 + j * 64 + i] = val;
  }
}

// ---------------------------------------------------------------------------
extern "C" void kernel_launch(void* const* d_in, const int* in_sizes, int n_in,
                              void* d_out, int out_size, void* d_ws, size_t ws_size,
                              hipStream_t stream)
{
  (void)in_sizes; (void)n_in; (void)out_size; (void)ws_size;

  const float* z       = (const float*)d_in[0];
  const int*   n_nodes = (const int*)d_in[1];
  // d_in[2] = n_edges (unused by reference)
  const float* gu      = (const float*)d_in[3];
  const float* emb     = (const float*)d_in[4];
  const float* pe      = (const float*)d_in[5];
  const float* W_pre   = (const float*)d_in[6];
  const float* b_pre   = (const float*)d_in[7];
  const float* Wih0    = (const float*)d_in[8];
  const float* Whh0    = (const float*)d_in[9];
  const float* bih0    = (const float*)d_in[10];
  const float* bhh0    = (const float*)d_in[11];
  const float* Wih1    = (const float*)d_in[12];
  const float* Whh1    = (const float*)d_in[13];
  const float* bih1    = (const float*)d_in[14];
  const float* bhh1    = (const float*)d_in[15];
  const float* node_W  = (const float*)d_in[16];
  const float* adj_W1  = (const float*)d_in[17];
  const float* adj_b1  = (const float*)d_in[18];
  const float* adj_W2  = (const float*)d_in[19];
  const float* adj_b2  = (const float*)d_in[20];
  float* adj = (float*)d_out;

  // workspace layout (bytes)
  char* ws = (char*)d_ws;
  float* ZC    = (float*)(ws + 0);          // 192 x 256          -> 196608
  float* ZCW   = (float*)(ws + 196608);     // 192 x 1536         -> 1376256
  float* WAB   = (float*)(ws + 1376256);    // 1024 x 512         -> 3473408
  float* WT    = (float*)(ws + 3473408);    // 3 x 512x512x4      -> 16056320
  float* Ht1   = (float*)(ws + 16056320);   // 2 x 512 x 128      -> 16580608
  float* H2t   = (float*)(ws + 16580608);   // 2 x 512 x 128      -> 17104896
  float* GIt   = (float*)(ws + 17104896);   // 2 x 1536 x 128     -> 18677760
  float* H2row = (float*)(ws + 18677760);   // 8192 x 512         -> 35454976
  float* AB    = (float*)(ws + 35454976);   // 8192 x 1024        -> 69009408

  // 1) ZC projections + diag zero + WAB + weight transposes (one launch)
  pre_kernel<<<736, 256, 0, stream>>>(z, pe, emb, W_pre, b_pre, ZC, adj,
                                      adj_W1, node_W, WAB,
                                      Whh0, Wih1, Whh1, WT);

  // 2) ZCW = ZC @ Wih0^T   (192 x 1536, K=256)
  gemm_kernel<false><<<dim3(12, 2), 256, 0, stream>>>(
      ZC, 256, Wih0, 256, nullptr, ZCW, 1536, 192, 1536, 256, nullptr);

  // 3) depth-3 pipelined GRU scan, streaming-dot kernel
  for (int s = 0; s <= 65; s++)
    gru_v5_kernel<<<dim3(256, 3), 512, 0, stream>>>(
        WT, ZCW, bih0, bhh0, bih1, bhh1, n_nodes,
        Ht1, GIt, H2t, H2row, s);

  // 4) AB = (mask * H2row) @ WAB^T   (8192 x 1024, K=512)
  gemm_kernel<true><<<dim3(8, 64), 256, 0, stream>>>(
      H2row, 512, WAB, 512, nullptr, AB, 1024, 8192, 1024, 512, n_nodes);

  // 5) output pairs (diagonal already zeroed in step 1)
  pair_kernel<<<64512, 256, 0, stream>>>(AB, adj_b1, adj_W2, adj_b2, gu, n_nodes, adj);
}

// Round 6
// 1945.229 us; speedup vs baseline: 1.7990x; 1.0427x over previous
//
#include <hip/hip_runtime.h>
#include <math.h>

#define LATENT 256
#define HIDDEN 512
#define MAXN   64
#define BATCH  128
#define NPAIR  2016   // 64*63/2
#define G3     1536   // 3*HIDDEN

// Ht / H2t ring slot stride (floats): [512 o][128 b]
#define HT_S   65536
// GIt ring slot stride (floats): [1536 r][128 b]
#define GIT_S  196608
// one transposed weight matrix WT[k][o][4] (floats)
#define WT_S   1048576

// ---------------------------------------------------------------------------
// pre_kernel:
//   blocks   0..191 -> ZC projections (+ adj diagonal zero in blocks 0..31)
//   blocks 192..447 -> WAB precompute (folded adj_W1 @ node_W)
//   blocks 448..735 -> weight transposes: WT[mat][k][o][g] = W[g*512+o][k]
//                      mat 0=Whh0, 1=Wih1, 2=Whh1  (pad g=3 unwritten/unused)
// ---------------------------------------------------------------------------
__global__ __launch_bounds__(256) void pre_kernel(
    const float* __restrict__ z, const float* __restrict__ pe,
    const float* __restrict__ emb, const float* __restrict__ W_pre,
    const float* __restrict__ b_pre, float* __restrict__ ZC,
    float* __restrict__ adj,
    const float* __restrict__ adj_W1, const float* __restrict__ node_W,
    float* __restrict__ WAB,
    const float* __restrict__ Whh0, const float* __restrict__ Wih1,
    const float* __restrict__ Whh1, float* __restrict__ WT)
{
  __shared__ float s1[256];
  __shared__ float s2[256];
  int blk = blockIdx.x;
  int o = threadIdx.x;      // 0..255
  if (blk < 192) {
    int row = blk;
    if (row < 32) {
      int x = row * 256 + o;            // 0..8191
      int b = x >> 6, d = x & 63;
      adj[(size_t)b * 4096 + d * 65] = 0.f;
    }
    const float* wr = W_pre + (size_t)o * 512;
    if (row < 128) {
      s1[o] = z[row * 256 + o];
      __syncthreads();
      float acc = 0.f;
      #pragma unroll 8
      for (int k = 0; k < 256; k += 4) {
        float4 w4 = *(const float4*)(wr + k);
        float4 x4 = *(const float4*)(&s1[k]);
        acc += x4.x * w4.x; acc += x4.y * w4.y; acc += x4.z * w4.z; acc += x4.w * w4.w;
      }
      ZC[row * 256 + o] = acc;
    } else {
      int m = row - 128;
      s1[o] = pe[m * 256 + o];
      s2[o] = emb[m * 256 + o];
      __syncthreads();
      float acc = b_pre[o];
      #pragma unroll 8
      for (int k = 0; k < 256; k += 4) {
        float4 w4 = *(const float4*)(wr + k);
        float4 x4 = *(const float4*)(&s1[k]);
        acc += x4.x * w4.x; acc += x4.y * w4.y; acc += x4.z * w4.z; acc += x4.w * w4.w;
      }
      #pragma unroll 8
      for (int k = 0; k < 256; k += 4) {
        float4 w4 = *(const float4*)(wr + 256 + k);
        float4 x4 = *(const float4*)(&s2[k]);
        acc += x4.x * w4.x; acc += x4.y * w4.y; acc += x4.z * w4.z; acc += x4.w * w4.w;
      }
      ZC[row * 256 + o] = acc;
    }
  } else if (blk < 448) {
    // WAB: idx in [0,256): kb = idx&1, o-group = (idx>>1)&63, sel = idx>>7
    int idx = blk - 192;
    int k = (idx & 1) * 256 + o;            // 0..511
    int o0 = ((idx >> 1) & 63) * 8;
    int sel = idx >> 7;
    const float* a1 = adj_W1 + (sel ? 512 : 0);
    float acc[8] = {0.f, 0.f, 0.f, 0.f, 0.f, 0.f, 0.f, 0.f};
    for (int j = 0; j < 512; j++) {
      float w = node_W[(size_t)j * 512 + k];
      #pragma unroll
      for (int oo = 0; oo < 8; oo++)
        acc[oo] += a1[(size_t)(o0 + oo) * 1024 + j] * w;
    }
    #pragma unroll
    for (int oo = 0; oo < 8; oo++)
      WAB[(size_t)(sel * 512 + o0 + oo) * 512 + k] = acc[oo];
  } else {
    // weight transpose: 288 blocks, each 16 rows of one 1536x512 matrix
    int idx2 = blk - 448;             // 0..287
    int mat = idx2 / 96;              // 0..2
    int r0 = (idx2 % 96) * 16;
    const float* Wsrc = (mat == 0) ? Whh0 : (mat == 1) ? Wih1 : Whh1;
    float* Wd = WT + (size_t)mat * WT_S;
    int r = r0 + (o >> 4);            // 16 rows, 16 threads per row
    int oo = r & 511, g = r >> 9;
    int k0 = (o & 15) * 32;
    const float* src = Wsrc + (size_t)r * 512 + k0;
    for (int k = 0; k < 32; k++)
      Wd[((size_t)(k0 + k) * 512 + oo) * 4 + g] = src[k];
  }
}

// ---------------------------------------------------------------------------
// Generic f32 GEMM: C[M,N] = A[M,K] @ W[N,K]^T (+bias), optional per-row mask
// blockIdx.x = ROW tile, blockIdx.y = COL tile (x fastest -> row tiles
// round-robin across XCDs: each XCD owns row stripes, A slice stays in its
// L2; only the small W (<=3 MB) is re-read by every XCD).
// Register-prefetch double buffering: next tile loads overlap the FMA loop.
// ---------------------------------------------------------------------------
template<bool MASK>
__global__ __launch_bounds__(256) void gemm_kernel(
    const float* __restrict__ A, int lda,
    const float* __restrict__ W, int ldw,
    const float* __restrict__ bias,
    float* __restrict__ C, int ldc,
    int M, int N, int K,
    const int* __restrict__ n_nodes)
{
  __shared__ float As[16][136];
  __shared__ float Ws[16][136];
  const int tid = threadIdx.x;
  const int tx = tid & 15, ty = tid >> 4;
  const int row0 = blockIdx.x * 128, col0 = blockIdx.y * 128;

  float acc[8][8];
  #pragma unroll
  for (int i = 0; i < 8; i++)
    #pragma unroll
    for (int j = 0; j < 8; j++) acc[i][j] = 0.f;

  float4 va[2], vw[2];
  auto load_tile = [&](int k0) {
    #pragma unroll
    for (int s = 0; s < 2; s++) {
      int q = tid + 256 * s;
      int r = q >> 2;
      int c4 = (q & 3) << 2;
      int gm = row0 + r;
      float4 v = make_float4(0.f, 0.f, 0.f, 0.f);
      if (gm < M) {
        v = *(const float4*)(A + (size_t)gm * lda + k0 + c4);
        if (MASK) {
          int bb = gm >> 6, tt = gm & 63;
          if (tt >= n_nodes[bb]) v = make_float4(0.f, 0.f, 0.f, 0.f);
        }
      }
      va[s] = v;
      int gn = col0 + r;
      vw[s] = *(const float4*)(W + (size_t)gn * ldw + k0 + c4);
    }
  };

  load_tile(0);
  for (int k0 = 0; k0 < K; k0 += 16) {
    __syncthreads();   // previous compute done reading LDS
    #pragma unroll
    for (int s = 0; s < 2; s++) {
      int q = tid + 256 * s;
      int r = q >> 2, c4 = (q & 3) << 2;
      As[c4 + 0][r] = va[s].x; As[c4 + 1][r] = va[s].y; As[c4 + 2][r] = va[s].z; As[c4 + 3][r] = va[s].w;
      Ws[c4 + 0][r] = vw[s].x; Ws[c4 + 1][r] = vw[s].y; Ws[c4 + 2][r] = vw[s].z; Ws[c4 + 3][r] = vw[s].w;
    }
    __syncthreads();
    if (k0 + 16 < K) load_tile(k0 + 16);   // overlaps the FMA loop below
    #pragma unroll
    for (int kk = 0; kk < 16; kk++) {
      float4 a0 = *(const float4*)&As[kk][ty * 8];
      float4 a1 = *(const float4*)&As[kk][ty * 8 + 4];
      float4 b0 = *(const float4*)&Ws[kk][tx * 8];
      float4 b1 = *(const float4*)&Ws[kk][tx * 8 + 4];
      float av[8] = {a0.x, a0.y, a0.z, a0.w, a1.x, a1.y, a1.z, a1.w};
      float bv[8] = {b0.x, b0.y, b0.z, b0.w, b1.x, b1.y, b1.z, b1.w};
      #pragma unroll
      for (int i = 0; i < 8; i++)
        #pragma unroll
        for (int j = 0; j < 8; j++)
          acc[i][j] += av[i] * bv[j];
    }
  }

  float bb[8];
  #pragma unroll
  for (int j = 0; j < 8; j++) bb[j] = bias ? bias[col0 + tx * 8 + j] : 0.f;
  #pragma unroll
  for (int i = 0; i < 8; i++) {
    int gm = row0 + ty * 8 + i;
    if (gm < M) {
      float* out = C + (size_t)gm * ldc + col0 + tx * 8;
      float4 o0 = make_float4(acc[i][0] + bb[0], acc[i][1] + bb[1], acc[i][2] + bb[2], acc[i][3] + bb[3]);
      float4 o1 = make_float4(acc[i][4] + bb[4], acc[i][5] + bb[5], acc[i][6] + bb[6], acc[i][7] + bb[7]);
      *(float4*)out = o0;
      *(float4*)(out + 4) = o1;
    }
  }
}

// ---------------------------------------------------------------------------
// v5 GRU step: 3 planes per launch, all-global streaming dot (NO LDS in the
// main loop), split-K across 8 waves, LDS only for the 8-way partial reduce.
//   plane 0: t=s    h1[t] = cell(h1[t-1]@Whh0^T, ZCW)      -> Ht1 ring
//   plane 1: t=s-1  GIt[t] = h1[t]@Wih1^T + bih1            -> GIt ring
//   plane 2: t=s-2  h2[t] = cell(h2[t-1]@Whh1^T, GIt[t])   -> H2t ring + H2row
// Block index decode (XCD-pinning): o-slice in the LOW 6 bits of blockIdx.x,
// b-split in the high bits. The 4 b-replicas of a WT o-slice sit at stride
// 64 (== 0 mod 8) -> same XCD under round-robin block->XCD dispatch, and the
// SAME o-slice maps to the SAME XCD in every launch -> each XCD's WT working
// set is 16MB/8 = 2 MB, L2-resident across all 66 launches (WT never
// changes). h (256 KB/plane) L2-caches per XCD on its own.
// ---------------------------------------------------------------------------
__global__ __launch_bounds__(512) void gru_v5_kernel(
    const float* __restrict__ WT,
    const float* __restrict__ ZCW,
    const float* __restrict__ bih0, const float* __restrict__ bhh0,
    const float* __restrict__ bih1, const float* __restrict__ bhh1,
    const int* __restrict__ n_nodes,
    float* __restrict__ Ht1, float* __restrict__ GIt,
    float* __restrict__ H2t, float* __restrict__ H2row,
    int s)
{
  __shared__ float p_s[8][3][8][32];   // 24 KB partials
  const int tid = threadIdx.x;
  const int plane = blockIdx.y;
  const int o0 = (blockIdx.x & 63) << 3;   // low bits: o-slice (XCD-pinned)
  const int b0 = (blockIdx.x >> 6) << 5;   // high bits: b-split

  int t; const float* Wmat; const float* Hin; bool dd;
  if (plane == 0)      { t = s;     Wmat = WT;            Hin = Ht1 + ((t - 1) & 1) * HT_S; dd = (t > 0); }
  else if (plane == 1) { t = s - 1; Wmat = WT + WT_S;     Hin = Ht1 + (t & 1) * HT_S;       dd = true; }
  else                 { t = s - 2; Wmat = WT + 2 * WT_S; Hin = H2t + ((t - 1) & 1) * HT_S; dd = (t > 0); }
  if (t < 0 || t > 63) return;

  float acc[3][4] = {{0.f, 0.f, 0.f, 0.f}, {0.f, 0.f, 0.f, 0.f}, {0.f, 0.f, 0.f, 0.f}};
  const int w = tid >> 6, l = tid & 63;
  const int bg = l & 7, rg = l >> 3;

  if (dd) {
    const float* hp_ = Hin + b0 + bg * 4 + (size_t)(w << 6) * 128;
    const float* wp_ = Wmat + (size_t)(o0 + rg) * 4 + (size_t)(w << 6) * 2048;
    #pragma unroll 4
    for (int k = 0; k < 64; k++) {
      float4 h4 = *(const float4*)(hp_ + (size_t)k * 128);
      float4 w4 = *(const float4*)(wp_ + (size_t)k * 2048);
      acc[0][0] += h4.x * w4.x; acc[0][1] += h4.y * w4.x; acc[0][2] += h4.z * w4.x; acc[0][3] += h4.w * w4.x;
      acc[1][0] += h4.x * w4.y; acc[1][1] += h4.y * w4.y; acc[1][2] += h4.z * w4.y; acc[1][3] += h4.w * w4.y;
      acc[2][0] += h4.x * w4.z; acc[2][1] += h4.y * w4.z; acc[2][2] += h4.z * w4.z; acc[2][3] += h4.w * w4.z;
    }
  }

  *(float4*)&p_s[w][0][rg][bg * 4] = make_float4(acc[0][0], acc[0][1], acc[0][2], acc[0][3]);
  *(float4*)&p_s[w][1][rg][bg * 4] = make_float4(acc[1][0], acc[1][1], acc[1][2], acc[1][3]);
  *(float4*)&p_s[w][2][rg][bg * 4] = make_float4(acc[2][0], acc[2][1], acc[2][2], acc[2][3]);
  __syncthreads();

  if (tid < 256) {
    int b = tid & 31, oi = tid >> 5;
    float s0 = 0.f, s1 = 0.f, s2 = 0.f;
    #pragma unroll
    for (int ww = 0; ww < 8; ww++) {
      s0 += p_s[ww][0][oi][b];
      s1 += p_s[ww][1][oi][b];
      s2 += p_s[ww][2][oi][b];
    }
    const int B = b0 + b, O = o0 + oi;

    if (plane == 0) {
      bool mk = t < n_nodes[B];
      float zr = mk ? ZCW[(size_t)B * G3 + O]        + ZCW[(size_t)(128 + t) * G3 + O]        : 0.f;
      float zz = mk ? ZCW[(size_t)B * G3 + 512 + O]  + ZCW[(size_t)(128 + t) * G3 + 512 + O]  : 0.f;
      float zn = mk ? ZCW[(size_t)B * G3 + 1024 + O] + ZCW[(size_t)(128 + t) * G3 + 1024 + O] : 0.f;
      float ir = zr + bih0[O], iz = zz + bih0[512 + O], inn = zn + bih0[1024 + O];
      float hr = s0 + bhh0[O], hz = s1 + bhh0[512 + O], hn = s2 + bhh0[1024 + O];
      float rg_ = 1.f / (1.f + expf(-(ir + hr)));
      float zg  = 1.f / (1.f + expf(-(iz + hz)));
      float ng  = tanhf(inn + rg_ * hn);
      float hp = (t > 0) ? Ht1[((t - 1) & 1) * HT_S + O * 128 + B] : 0.f;
      Ht1[(t & 1) * HT_S + O * 128 + B] = (1.f - zg) * ng + zg * hp;
    } else if (plane == 1) {
      size_t gb = (size_t)(t & 1) * GIT_S;
      GIt[gb + (size_t)O * 128 + B]          = s0 + bih1[O];
      GIt[gb + (size_t)(512 + O) * 128 + B]  = s1 + bih1[512 + O];
      GIt[gb + (size_t)(1024 + O) * 128 + B] = s2 + bih1[1024 + O];
    } else {
      size_t gb = (size_t)(t & 1) * GIT_S;
      float ir  = GIt[gb + (size_t)O * 128 + B];
      float iz  = GIt[gb + (size_t)(512 + O) * 128 + B];
      float inn = GIt[gb + (size_t)(1024 + O) * 128 + B];
      float hr = s0 + bhh1[O], hz = s1 + bhh1[512 + O], hn = s2 + bhh1[1024 + O];
      float rg_ = 1.f / (1.f + expf(-(ir + hr)));
      float zg  = 1.f / (1.f + expf(-(iz + hz)));
      float ng  = tanhf(inn + rg_ * hn);
      float hp = (t > 0) ? H2t[((t - 1) & 1) * HT_S + O * 128 + B] : 0.f;
      float hnew = (1.f - zg) * ng + zg * hp;
      H2t[(t & 1) * HT_S + O * 128 + B] = hnew;
      H2row[((size_t)(B * 64 + t)) * 512 + O] = hnew;
    }
  }
}

// ---------------------------------------------------------------------------
// Pair kernel: one wave per (b, pair). Early-exit (wave-uniform) for masked
// pairs (~66% on average) before touching AB.
// ---------------------------------------------------------------------------
__global__ __launch_bounds__(256) void pair_kernel(
    const float* __restrict__ AB, const float* __restrict__ b1,
    const float* __restrict__ W2, const float* __restrict__ b2,
    const float* __restrict__ gu, const int* __restrict__ n_nodes,
    float* __restrict__ adj)
{
  int wid = blockIdx.x * 4 + (threadIdx.x >> 6);
  int lane = threadIdx.x & 63;
  int b = wid / NPAIR;
  int p = wid - b * NPAIR;

  float fp = (float)p;
  int i = (int)((127.0f - sqrtf(16129.0f - 8.0f * fp)) * 0.5f);
  if (i < 0) i = 0;
  if (i > 62) i = 62;
  while (i < 62 && (i + 1) * (126 - i) / 2 <= p) i++;
  while (i > 0 && i * (127 - i) / 2 > p) i--;
  int j = p - i * (127 - i) / 2 + i + 1;

  int n = n_nodes[b];
  if (i >= n || j >= n) {          // wave-uniform: whole wave skips the dot
    if (lane == 0) {
      adj[(size_t)b * 4096 + i * 64 + j] = 0.f;
      adj[(size_t)b * 4096 + j * 64 + i] = 0.f;
    }
    return;
  }

  const float* arow = AB + ((size_t)(b * 64 + i)) * 1024;
  const float* brow = AB + ((size_t)(b * 64 + j)) * 1024 + 512;
  int k0 = lane * 8;

  float4 a0 = *(const float4*)(arow + k0);
  float4 a1 = *(const float4*)(arow + k0 + 4);
  float4 q0 = *(const float4*)(brow + k0);
  float4 q1 = *(const float4*)(brow + k0 + 4);
  float4 c0 = *(const float4*)(b1 + k0);
  float4 c1 = *(const float4*)(b1 + k0 + 4);

  float h0 = fmaxf(a0.x + q0.x + c0.x, 0.f);
  float h1 = fmaxf(a0.y + q0.y + c0.y, 0.f);
  float h2 = fmaxf(a0.z + q0.z + c0.z, 0.f);
  float h3 = fmaxf(a0.w + q0.w + c0.w, 0.f);
  float h4 = fmaxf(a1.x + q1.x + c1.x, 0.f);
  float h5 = fmaxf(a1.y + q1.y + c1.y, 0.f);
  float h6 = fmaxf(a1.z + q1.z + c1.z, 0.f);
  float h7 = fmaxf(a1.w + q1.w + c1.w, 0.f);

  float4 w00 = *(const float4*)(W2 + k0);
  float4 w01 = *(const float4*)(W2 + k0 + 4);
  float4 w10 = *(const float4*)(W2 + 512 + k0);
  float4 w11 = *(const float4*)(W2 + 512 + k0 + 4);

  float acc0 = h0 * w00.x + h1 * w00.y + h2 * w00.z + h3 * w00.w
             + h4 * w01.x + h5 * w01.y + h6 * w01.z + h7 * w01.w;
  float acc1 = h0 * w10.x + h1 * w10.y + h2 * w10.z + h3 * w10.w
             + h4 * w11.x + h5 * w11.y + h6 * w11.z + h7 * w11.w;

  #pragma unroll
  for (int off = 32; off > 0; off >>= 1) {
    acc0 += __shfl_xor(acc0, off, 64);
    acc1 += __shfl_xor(acc1, off, 64);
  }

  if (lane == 0) {
    float s0 = acc0 + b2[0];
    float s1 = acc1 + b2[1];
    const float* u = gu + ((size_t)(b * NPAIR + p)) * 2;
    float g0 = -logf(-logf(u[0] + 1e-10f) + 1e-10f);
    float g1 = -logf(-logf(u[1] + 1e-10f) + 1e-10f);
    float val = ((s0 + g0) >= (s1 + g1)) ? 1.f : 0.f;
    adj[(size_t)b * 4096 + i * 64 + j] = val;
    adj[(size_t)b * 4096 + j * 64 + i] = val;
  }
}

// ---------------------------------------------------------------------------
extern "C" void kernel_launch(void* const* d_in, const int* in_sizes, int n_in,
                              void* d_out, int out_size, void* d_ws, size_t ws_size,
                              hipStream_t stream)
{
  (void)in_sizes; (void)n_in; (void)out_size; (void)ws_size;

  const float* z       = (const float*)d_in[0];
  const int*   n_nodes = (const int*)d_in[1];
  // d_in[2] = n_edges (unused by reference)
  const float* gu      = (const float*)d_in[3];
  const float* emb     = (const float*)d_in[4];
  const float* pe      = (const float*)d_in[5];
  const float* W_pre   = (const float*)d_in[6];
  const float* b_pre   = (const float*)d_in[7];
  const float* Wih0    = (const float*)d_in[8];
  const float* Whh0    = (const float*)d_in[9];
  const float* bih0    = (const float*)d_in[10];
  const float* bhh0    = (const float*)d_in[11];
  const float* Wih1    = (const float*)d_in[12];
  const float* Whh1    = (const float*)d_in[13];
  const float* bih1    = (const float*)d_in[14];
  const float* bhh1    = (const float*)d_in[15];
  const float* node_W  = (const float*)d_in[16];
  const float* adj_W1  = (const float*)d_in[17];
  const float* adj_b1  = (const float*)d_in[18];
  const float* adj_W2  = (const float*)d_in[19];
  const float* adj_b2  = (const float*)d_in[20];
  float* adj = (float*)d_out;

  // workspace layout (bytes)
  char* ws = (char*)d_ws;
  float* ZC    = (float*)(ws + 0);          // 192 x 256          -> 196608
  float* ZCW   = (float*)(ws + 196608);     // 192 x 1536         -> 1376256
  float* WAB   = (float*)(ws + 1376256);    // 1024 x 512         -> 3473408
  float* WT    = (float*)(ws + 3473408);    // 3 x 512x512x4      -> 16056320
  float* Ht1   = (float*)(ws + 16056320);   // 2 x 512 x 128      -> 16580608
  float* H2t   = (float*)(ws + 16580608);   // 2 x 512 x 128      -> 17104896
  float* GIt   = (float*)(ws + 17104896);   // 2 x 1536 x 128     -> 18677760
  float* H2row = (float*)(ws + 18677760);   // 8192 x 512         -> 35454976
  float* AB    = (float*)(ws + 35454976);   // 8192 x 1024        -> 69009408

  // 1) ZC projections + diag zero + WAB + weight transposes (one launch)
  pre_kernel<<<736, 256, 0, stream>>>(z, pe, emb, W_pre, b_pre, ZC, adj,
                                      adj_W1, node_W, WAB,
                                      Whh0, Wih1, Whh1, WT);

  // 2) ZCW = ZC @ Wih0^T   (192 x 1536, K=256); grid = (rowTiles, colTiles)
  gemm_kernel<false><<<dim3(2, 12), 256, 0, stream>>>(
      ZC, 256, Wih0, 256, nullptr, ZCW, 1536, 192, 1536, 256, nullptr);

  // 3) depth-3 pipelined GRU scan, streaming-dot kernel (XCD-pinned WT)
  for (int s = 0; s <= 65; s++)
    gru_v5_kernel<<<dim3(256, 3), 512, 0, stream>>>(
        WT, ZCW, bih0, bhh0, bih1, bhh1, n_nodes,
        Ht1, GIt, H2t, H2row, s);

  // 4) AB = (mask * H2row) @ WAB^T   (8192 x 1024, K=512); grid = (rows, cols)
  gemm_kernel<true><<<dim3(64, 8), 256, 0, stream>>>(
      H2row, 512, WAB, 512, nullptr, AB, 1024, 8192, 1024, 512, n_nodes);

  // 5) output pairs (diagonal already zeroed in step 1)
  pair_kernel<<<64512, 256, 0, stream>>>(AB, adj_b1, adj_W2, adj_b2, gu, n_nodes, adj);
}